// Round 2
// baseline (1247.577 us; speedup 1.0000x reference)
//
#include <hip/hip_runtime.h>

#define M_EDGES 150000
#define NN_NODES 50000
#define N_TRIS  100000
#define F 256
#define NLAYERS 4

// unified GEMM: virtual A = [x (150k) ; s (50k) ; q (100k)], 256 cols each
#define T0 1172                  // ceil(150000/128)
#define T1 391                   // ceil(50000/128)
#define T2 782                   // ceil(100000/128)
#define NTILES (T0 + T1 + T2)    // 2345
#define NT_PAD 2352              // 8 * ceil(NTILES/8)

typedef __attribute__((ext_vector_type(8))) __bf16 bf16x8;
typedef __attribute__((ext_vector_type(4))) float f32x4;

__device__ inline unsigned short f2bf(float f) {
    unsigned int u = __float_as_uint(f);
    u += 0x7fff + ((u >> 16) & 1);
    return (unsigned short)(u >> 16);
}
__device__ inline float bf2f(unsigned short h) {
    return __uint_as_float(((unsigned int)h) << 16);
}

__device__ inline void async16(const void* g, void* l) {
    __builtin_amdgcn_global_load_lds(
        (const __attribute__((address_space(1))) void*)g,
        (__attribute__((address_space(3))) void*)l, 16, 0, 0);
}

// ---------------------------------------------------------------------------
// Unified bf16 MFMA GEMM over 3 row-segments:
//   seg0: y1 = x @ W1   (150000 rows)
//   seg1: z  = s @ W0   (50000 rows)   [B1 pushed through W0]
//   seg2: w  = q @ W2   (100000 rows)  [B2^T pushed through W2]
// Weights wt layout: [seg][n][k] (n-major, 256x256 per seg).
// XCD swizzle: xcd=b&7, c=b>>3, tile=(c/2)*8+xcd, bn=c%2 -> both bn blocks of
// a tile share an XCD L2. XOR-swizzled LDS (conflict-free). Epilogue uses
// SWAPPED mfma operands -> lane holds 4 consecutive output cols -> ushort4
// stores.
//
// R2: T4 counted-vmcnt pipeline. R1 (double-buffer + vmcnt(0) per step) was
// NULL -- matches learn_hip m218: dbuf-with-drain0 == 1-phase; the gain IS
// the counted wait. Now: 3 LDS buffers, prefetch depth 2, wait vmcnt(4)
// (one chunk may remain in flight), raw s_barrier per phase, STAGE issued
// immediately after the barrier (issue-early). Chunk c lives in buf[c%3];
// phase t overwrites buf[(t+2)%3] which holds chunk t-1, consumed before
// this phase's barrier -> single barrier per phase is race-free.
// ---------------------------------------------------------------------------
__global__ __launch_bounds__(256) void gemm_mfma(
    const unsigned short* __restrict__ xb,
    const unsigned short* __restrict__ sb,
    const unsigned short* __restrict__ qb,
    const unsigned short* __restrict__ wt,
    unsigned short* __restrict__ y1,
    unsigned short* __restrict__ zb,
    unsigned short* __restrict__ wb)
{
    __shared__ unsigned short As[3][128 * 32];
    __shared__ unsigned short Bs[3][128 * 32];

    const int b    = blockIdx.x;
    const int xcd  = b & 7;
    const int c    = b >> 3;
    const int tile = (c >> 1) * 8 + xcd;
    const int bn   = c & 1;
    if (tile >= NTILES) return;

    int seg, tloc;
    if (tile < T0)            { seg = 0; tloc = tile; }
    else if (tile < T0 + T1)  { seg = 1; tloc = tile - T0; }
    else                      { seg = 2; tloc = tile - T0 - T1; }
    const unsigned short* Asrc = (seg == 0) ? xb : (seg == 1) ? sb : qb;
    const int nrows = (seg == 0) ? M_EDGES : (seg == 1) ? NN_NODES : N_TRIS;
    const unsigned short* wsel = wt + seg * 65536;
    unsigned short* dst = (seg == 0) ? y1 : (seg == 1) ? zb : wb;

    const int tid  = threadIdx.x;
    const int bm0  = tloc * 128;
    const int wid  = tid >> 6;
    const int lane = tid & 63;
    const int lm   = lane & 15;
    const int lh   = lane >> 4;
    const int wm   = wid >> 1;
    const int wn   = wid & 1;
    const int wbase = tid & ~63;

    f32x4 cacc[4][4];
#pragma unroll
    for (int i = 0; i < 4; i++)
#pragma unroll
        for (int j = 0; j < 4; j++) cacc[i][j] = (f32x4){0.f, 0.f, 0.f, 0.f};

// issue one K-chunk's staging loads into buffer bi (4 x 16B per thread)
#define STAGE(bi, k0)                                                       \
    do {                                                                    \
        _Pragma("unroll")                                                   \
        for (int ss = 0; ss < 2; ss++) {                                    \
            int ii  = ss * 256 + tid;                                       \
            int row = ii >> 2;                                              \
            int g   = (ii & 3) ^ ((row >> 1) & 3);                          \
            int gr  = bm0 + row;                                            \
            if (gr > nrows - 1) gr = nrows - 1;                             \
            async16(Asrc + (size_t)gr * 256 + (k0) + g * 8,                 \
                    As[bi] + (size_t)(ss * 256 + wbase) * 8);               \
            int nrow = bn * 128 + row;                                      \
            async16(wsel + (size_t)nrow * 256 + (k0) + g * 8,               \
                    Bs[bi] + (size_t)(ss * 256 + wbase) * 8);               \
        }                                                                   \
    } while (0)

// fragment loads + 16 MFMA from buffer bi
#define COMPUTE(bi)                                                         \
    do {                                                                    \
        bf16x8 a[4], bfr[4];                                                \
        _Pragma("unroll")                                                   \
        for (int i = 0; i < 4; i++) {                                       \
            int rr = wm * 64 + i * 16 + lm;                                 \
            a[i] = *(const bf16x8*)(As[bi] + rr * 32 +                      \
                                    ((lh ^ ((rr >> 1) & 3)) * 8));          \
        }                                                                   \
        _Pragma("unroll")                                                   \
        for (int j = 0; j < 4; j++) {                                       \
            int rr = wn * 64 + j * 16 + lm;                                 \
            bfr[j] = *(const bf16x8*)(Bs[bi] + rr * 32 +                    \
                                      ((lh ^ ((rr >> 1) & 3)) * 8));        \
        }                                                                   \
        __builtin_amdgcn_s_setprio(1);                                      \
        _Pragma("unroll")                                                   \
        for (int i = 0; i < 4; i++)                                         \
            _Pragma("unroll")                                               \
            for (int j = 0; j < 4; j++)                                     \
                cacc[i][j] = __builtin_amdgcn_mfma_f32_16x16x32_bf16(       \
                    bfr[j], a[i], cacc[i][j], 0, 0, 0);                     \
        __builtin_amdgcn_s_setprio(0);                                      \
    } while (0)

// counted wait: allow N VMEM ops (= N/4 chunks) to remain in flight, then
// barrier so every wave's chunk-t loads are visible in LDS. Raw s_barrier:
// no compiler lgkm/vm drain.
#define WAITP(N)                                                            \
    do {                                                                    \
        asm volatile("s_waitcnt vmcnt(" #N ")" ::: "memory");               \
        __builtin_amdgcn_s_barrier();                                       \
        asm volatile("" ::: "memory");                                      \
    } while (0)

    STAGE(0, 0);
    STAGE(1, 32);

    WAITP(4);  STAGE(2, 64);   COMPUTE(0);   // phase 0: chunk 0, c2 in flight
    WAITP(4);  STAGE(0, 96);   COMPUTE(1);   // phase 1
    WAITP(4);  STAGE(1, 128);  COMPUTE(2);   // phase 2
    WAITP(4);  STAGE(2, 160);  COMPUTE(0);   // phase 3
    WAITP(4);  STAGE(0, 192);  COMPUTE(1);   // phase 4
    WAITP(4);  STAGE(1, 224);  COMPUTE(2);   // phase 5
    WAITP(4);                  COMPUTE(0);   // phase 6: c7 still in flight
    WAITP(0);                  COMPUTE(1);   // phase 7: drain

#undef STAGE
#undef COMPUTE
#undef WAITP

#pragma unroll
    for (int i = 0; i < 4; i++) {
        int grow = bm0 + wm * 64 + i * 16 + lm;
        if (grow < nrows) {
#pragma unroll
            for (int j = 0; j < 4; j++) {
                int col = bn * 128 + wn * 64 + j * 16 + lh * 4;
                ushort4 r;
                r.x = f2bf(cacc[i][j][0]);
                r.y = f2bf(cacc[i][j][1]);
                r.z = f2bf(cacc[i][j][2]);
                r.w = f2bf(cacc[i][j][3]);
                *(ushort4*)(dst + (size_t)grow * 256 + col) = r;
            }
        }
    }
}

// ---------------------------------------------------------------------------
// CSR build
// ---------------------------------------------------------------------------
__global__ __launch_bounds__(256) void count_nodes(
    const int* __restrict__ en, int* __restrict__ cnt)
{
    int e = blockIdx.x * 256 + threadIdx.x;
    if (e < M_EDGES) {
        atomicAdd(&cnt[en[2 * e]], 1);
        atomicAdd(&cnt[en[2 * e + 1]], 1);
    }
}

__global__ __launch_bounds__(256) void count_tris(
    const int* __restrict__ te, int* __restrict__ cnt)
{
    int t = blockIdx.x * 256 + threadIdx.x;
    if (t < N_TRIS) {
#pragma unroll
        for (int k = 0; k < 3; k++) atomicAdd(&cnt[te[3 * t + k]], 1);
    }
}

__global__ __launch_bounds__(256) void scan_block(
    const int* __restrict__ cnt, int* __restrict__ off,
    int* __restrict__ partial, int n)
{
    __shared__ int s[256];
    int t = threadIdx.x;
    int gid = blockIdx.x * 256 + t;
    int v = (gid < n) ? cnt[gid] : 0;
    s[t] = v;
    __syncthreads();
    for (int o = 1; o < 256; o <<= 1) {
        int x = (t >= o) ? s[t - o] : 0;
        __syncthreads();
        s[t] += x;
        __syncthreads();
    }
    if (gid < n) off[gid] = s[t] - v;
    if (t == 255) partial[blockIdx.x] = s[255];
}

__global__ __launch_bounds__(1024) void scan_partial(int* __restrict__ partial, int nb)
{
    __shared__ int s[1024];
    int t = threadIdx.x;
    int v = (t < nb) ? partial[t] : 0;
    s[t] = v;
    __syncthreads();
    for (int o = 1; o < 1024; o <<= 1) {
        int x = (t >= o) ? s[t - o] : 0;
        __syncthreads();
        s[t] += x;
        __syncthreads();
    }
    if (t < nb) partial[t] = s[t] - v;
}

__global__ __launch_bounds__(256) void scan_add(
    int* __restrict__ off, int* __restrict__ cursor,
    const int* __restrict__ partial, int n, int total)
{
    int gid = blockIdx.x * 256 + threadIdx.x;
    if (gid == 0) off[n] = total;
    if (gid < n) {
        int o = off[gid] + partial[blockIdx.x];
        off[gid] = o;
        cursor[gid] = o;
    }
}

__global__ __launch_bounds__(256) void fill_nodes(
    const int* __restrict__ en, int* __restrict__ cursor, int* __restrict__ adj)
{
    int e = blockIdx.x * 256 + threadIdx.x;
    if (e < M_EDGES) {
        int u = en[2 * e], v = en[2 * e + 1];
        adj[atomicAdd(&cursor[u], 1)] = (e << 1);        // u endpoint: minus
        adj[atomicAdd(&cursor[v], 1)] = (e << 1) | 1;    // v endpoint: plus
    }
}

__global__ __launch_bounds__(256) void fill_tris(
    const int* __restrict__ te, const int* __restrict__ ts,
    int* __restrict__ cursor, int* __restrict__ adj)
{
    int t = blockIdx.x * 256 + threadIdx.x;
    if (t < N_TRIS) {
#pragma unroll
        for (int k = 0; k < 3; k++) {
            int e = te[3 * t + k];
            int neg = (ts[3 * t + k] < 0) ? 1 : 0;
            adj[atomicAdd(&cursor[e], 1)] = (t << 1) | neg;
        }
    }
}

// ---------------------------------------------------------------------------
// Aggregation pass (pre-GEMM):
//   blocks [0, ZN_BLOCKS)        : s[n] = sum (+/-) x[e]   (node CSR)
//   blocks [ZN_BLOCKS, +WT)      : q[t] = sum s_k * x[e_k] (tri direct)
// ---------------------------------------------------------------------------
#define ZN_BLOCKS (NN_NODES / 4)
#define WT_BLOCKS (N_TRIS / 4)

__global__ __launch_bounds__(256) void agg_fused(
    const unsigned short* __restrict__ xb,
    const int* __restrict__ noff,
    const int* __restrict__ nadj,
    unsigned short* __restrict__ sbuf,
    const int* __restrict__ te,
    const int* __restrict__ ts,
    unsigned short* __restrict__ qbuf)
{
    int lane = threadIdx.x & 63;
    int f = lane * 4;
    if (blockIdx.x < ZN_BLOCKS) {
        int n = blockIdx.x * 4 + (threadIdx.x >> 6);
        int beg = noff[n], end = noff[n + 1];
        float ax = 0.f, ay = 0.f, az = 0.f, aw = 0.f;
        int i = beg;
        for (; i + 1 < end; i += 2) {
            int ea = nadj[i], eb = nadj[i + 1];
            float sa = (ea & 1) ? 1.f : -1.f;
            float sgb = (eb & 1) ? 1.f : -1.f;
            ushort4 va = *(const ushort4*)(xb + (size_t)(ea >> 1) * 256 + f);
            ushort4 vb = *(const ushort4*)(xb + (size_t)(eb >> 1) * 256 + f);
            ax += sa * bf2f(va.x) + sgb * bf2f(vb.x);
            ay += sa * bf2f(va.y) + sgb * bf2f(vb.y);
            az += sa * bf2f(va.z) + sgb * bf2f(vb.z);
            aw += sa * bf2f(va.w) + sgb * bf2f(vb.w);
        }
        if (i < end) {
            int ea = nadj[i];
            float sa = (ea & 1) ? 1.f : -1.f;
            ushort4 va = *(const ushort4*)(xb + (size_t)(ea >> 1) * 256 + f);
            ax += sa * bf2f(va.x);
            ay += sa * bf2f(va.y);
            az += sa * bf2f(va.z);
            aw += sa * bf2f(va.w);
        }
        ushort4 r;
        r.x = f2bf(ax); r.y = f2bf(ay); r.z = f2bf(az); r.w = f2bf(aw);
        *(ushort4*)(sbuf + (size_t)n * 256 + f) = r;
    } else {
        int t = (blockIdx.x - ZN_BLOCKS) * 4 + (threadIdx.x >> 6);
        int e0 = te[3 * t + 0], e1 = te[3 * t + 1], e2 = te[3 * t + 2];
        float s0 = (float)ts[3 * t + 0];
        float s1 = (float)ts[3 * t + 1];
        float s2 = (float)ts[3 * t + 2];
        ushort4 a4 = *(const ushort4*)(xb + (size_t)e0 * 256 + f);
        ushort4 b4 = *(const ushort4*)(xb + (size_t)e1 * 256 + f);
        ushort4 d4 = *(const ushort4*)(xb + (size_t)e2 * 256 + f);
        ushort4 r;
        r.x = f2bf(s0 * bf2f(a4.x) + s1 * bf2f(b4.x) + s2 * bf2f(d4.x));
        r.y = f2bf(s0 * bf2f(a4.y) + s1 * bf2f(b4.y) + s2 * bf2f(d4.y));
        r.z = f2bf(s0 * bf2f(a4.z) + s1 * bf2f(b4.z) + s2 * bf2f(d4.z));
        r.w = f2bf(s0 * bf2f(a4.w) + s1 * bf2f(b4.w) + s2 * bf2f(d4.w));
        *(ushort4*)(qbuf + (size_t)t * 256 + f) = r;
    }
}

// ---------------------------------------------------------------------------
// x_next[e] = relu( y1[e] + sum s*w[t] + z[v]-z[u] )
// ---------------------------------------------------------------------------
__global__ __launch_bounds__(256) void relu_fused(
    const unsigned short* __restrict__ y1,
    const unsigned short* __restrict__ w,
    const unsigned short* __restrict__ z,
    const int* __restrict__ en,
    const int* __restrict__ eoff,
    const int* __restrict__ eadj,
    unsigned short* __restrict__ xb)
{
    int e = blockIdx.x * 4 + (threadIdx.x >> 6);
    int lane = threadIdx.x & 63;
    int f = lane * 4;
    int u = en[2 * e], v = en[2 * e + 1];
    int beg = eoff[e], end = eoff[e + 1];
    ushort4 a4 = *(const ushort4*)(y1 + (size_t)e * 256 + f);
    ushort4 zv = *(const ushort4*)(z + (size_t)v * 256 + f);
    ushort4 zu = *(const ushort4*)(z + (size_t)u * 256 + f);
    float sx = bf2f(a4.x) + bf2f(zv.x) - bf2f(zu.x);
    float sy = bf2f(a4.y) + bf2f(zv.y) - bf2f(zu.y);
    float sz = bf2f(a4.z) + bf2f(zv.z) - bf2f(zu.z);
    float sw = bf2f(a4.w) + bf2f(zv.w) - bf2f(zu.w);
    int i = beg;
    for (; i + 1 < end; i += 2) {
        int ta = eadj[i], tb = eadj[i + 1];
        float sa = (ta & 1) ? -1.f : 1.f;
        float sgb = (tb & 1) ? -1.f : 1.f;
        ushort4 wa = *(const ushort4*)(w + (size_t)(ta >> 1) * 256 + f);
        ushort4 wbv = *(const ushort4*)(w + (size_t)(tb >> 1) * 256 + f);
        sx += sa * bf2f(wa.x) + sgb * bf2f(wbv.x);
        sy += sa * bf2f(wa.y) + sgb * bf2f(wbv.y);
        sz += sa * bf2f(wa.z) + sgb * bf2f(wbv.z);
        sw += sa * bf2f(wa.w) + sgb * bf2f(wbv.w);
    }
    if (i < end) {
        int ta = eadj[i];
        float sa = (ta & 1) ? -1.f : 1.f;
        ushort4 wa = *(const ushort4*)(w + (size_t)(ta >> 1) * 256 + f);
        sx += sa * bf2f(wa.x);
        sy += sa * bf2f(wa.y);
        sz += sa * bf2f(wa.z);
        sw += sa * bf2f(wa.w);
    }
    ushort4 r;
    r.x = f2bf(fmaxf(sx, 0.f));
    r.y = f2bf(fmaxf(sy, 0.f));
    r.z = f2bf(fmaxf(sz, 0.f));
    r.w = f2bf(fmaxf(sw, 0.f));
    *(ushort4*)(xb + (size_t)e * 256 + f) = r;
}

// ---------------------------------------------------------------------------
// p[e] = x[e] . W0_L ; out[n] = sum (+/-) p[e]
// ---------------------------------------------------------------------------
__global__ __launch_bounds__(256) void dotp(
    const unsigned short* __restrict__ xb,
    const float* __restrict__ wl,
    float* __restrict__ p)
{
    int e = blockIdx.x * 4 + (threadIdx.x >> 6);
    int lane = threadIdx.x & 63;
    ushort4 xv = *(const ushort4*)(xb + (size_t)e * 256 + lane * 4);
    float4 wv = *(const float4*)(wl + lane * 4);
    float s = bf2f(xv.x) * wv.x + bf2f(xv.y) * wv.y +
              bf2f(xv.z) * wv.z + bf2f(xv.w) * wv.w;
#pragma unroll
    for (int off = 32; off > 0; off >>= 1)
        s += __shfl_down(s, off, 64);
    if (lane == 0) p[e] = s;
}

__global__ __launch_bounds__(256) void out_nodes(
    const float* __restrict__ p,
    const int* __restrict__ noff,
    const int* __restrict__ nadj,
    float* __restrict__ out)
{
    int n = blockIdx.x * 256 + threadIdx.x;
    if (n >= NN_NODES) return;
    int beg = noff[n], end = noff[n + 1];
    float s = 0.f;
    for (int i = beg; i < end; i++) {
        int ent = nadj[i];
        float sg = (ent & 1) ? 1.f : -1.f;
        s += sg * p[ent >> 1];
    }
    out[n] = s;
}

// ---------------------------------------------------------------------------
// Conversions
// ---------------------------------------------------------------------------
__global__ __launch_bounds__(256) void cvt_x(
    const float* __restrict__ x, unsigned short* __restrict__ xb)
{
    int idx = blockIdx.x * 256 + threadIdx.x;
    float4 v = *(const float4*)(x + (size_t)idx * 4);
    ushort4 r;
    r.x = f2bf(v.x); r.y = f2bf(v.y); r.z = f2bf(v.z); r.w = f2bf(v.w);
    *(ushort4*)(xb + (size_t)idx * 4) = r;
}

// wt[l][seg][n][k], seg order = (W1, W0, W2) matching GEMM segments
__global__ __launch_bounds__(256) void cvt_w(
    const float* __restrict__ W0, const float* __restrict__ W1,
    const float* __restrict__ W2, unsigned short* __restrict__ wt)
{
    int idx = blockIdx.x * 256 + threadIdx.x;   // 4*3*65536 total
    int l = idx / (3 * 65536);
    int rem = idx - l * (3 * 65536);
    int seg = rem >> 16;
    int n = (rem >> 8) & 255;
    int k = rem & 255;
    const float* src = (seg == 0) ? W1 : (seg == 1) ? W0 : W2;
    wt[idx] = f2bf(src[(size_t)l * 65536 + k * 256 + n]);
}

extern "C" void kernel_launch(void* const* d_in, const int* in_sizes, int n_in,
                              void* d_out, int out_size, void* d_ws, size_t ws_size,
                              hipStream_t stream)
{
    const float* x0  = (const float*)d_in[0];
    const float* W0s = (const float*)d_in[1];
    const float* W1s = (const float*)d_in[2];
    const float* W2s = (const float*)d_in[3];
    const float* WL  = (const float*)d_in[4];
    const int*   en  = (const int*)d_in[5];
    const int*   te  = (const int*)d_in[6];
    const int*   ts  = (const int*)d_in[7];
    float* out = (float*)d_out;

    const size_t MF = (size_t)M_EDGES * F;
    unsigned short* xb = (unsigned short*)d_ws;          // MF
    unsigned short* y1 = xb + MF;                        // MF
    unsigned short* sbuf = y1 + MF;                      // NN*256
    unsigned short* qbuf = sbuf + (size_t)NN_NODES * 256;// N_TRIS*256
    unsigned short* wt = qbuf + (size_t)N_TRIS * 256;    // 4*3*65536
    unsigned short* wb = wt + (size_t)4 * 3 * 65536;     // N_TRIS*256
    unsigned short* zb = wb + (size_t)N_TRIS * 256;      // NN*256
    float* p = (float*)(zb + (size_t)NN_NODES * 256);    // M f32
    int* noff = (int*)(p + M_EDGES);                     // NN+1
    int* ncur = noff + (NN_NODES + 1);                   // NN
    int* nadj = ncur + NN_NODES;                         // 2*M
    int* eoff = nadj + 2 * M_EDGES;                      // M+1
    int* ecur = eoff + (M_EDGES + 1);                    // M
    int* eadj = ecur + M_EDGES;                          // 3*N_TRIS
    int* part = eadj + 3 * N_TRIS;                       // 1024

    cvt_w<<<(4 * 3 * 65536) / 256, 256, 0, stream>>>(W0s, W1s, W2s, wt);
    cvt_x<<<(int)(MF / 4 / 256), 256, 0, stream>>>(x0, xb);

    const int nbN = (NN_NODES + 255) / 256;
    const int nbE = (M_EDGES + 255) / 256;
    hipMemsetAsync(ncur, 0, NN_NODES * sizeof(int), stream);
    hipMemsetAsync(ecur, 0, M_EDGES * sizeof(int), stream);
    count_nodes<<<nbE, 256, 0, stream>>>(en, ncur);
    count_tris<<<(N_TRIS + 255) / 256, 256, 0, stream>>>(te, ecur);
    scan_block<<<nbN, 256, 0, stream>>>(ncur, noff, part, NN_NODES);
    scan_partial<<<1, 1024, 0, stream>>>(part, nbN);
    scan_add<<<nbN, 256, 0, stream>>>(noff, ncur, part, NN_NODES, 2 * M_EDGES);
    fill_nodes<<<nbE, 256, 0, stream>>>(en, ncur, nadj);
    scan_block<<<nbE, 256, 0, stream>>>(ecur, eoff, part, M_EDGES);
    scan_partial<<<1, 1024, 0, stream>>>(part, nbE);
    scan_add<<<nbE, 256, 0, stream>>>(eoff, ecur, part, M_EDGES, 3 * N_TRIS);
    fill_tris<<<(N_TRIS + 255) / 256, 256, 0, stream>>>(te, ts, ecur, eadj);

    const int gemm_blocks = NT_PAD * 2;   // 4704
    for (int l = 0; l < NLAYERS; l++) {
        agg_fused<<<ZN_BLOCKS + WT_BLOCKS, 256, 0, stream>>>(
            xb, noff, nadj, sbuf, te, ts, qbuf);
        gemm_mfma<<<gemm_blocks, 256, 0, stream>>>(
            xb, sbuf, qbuf, wt + (size_t)l * 3 * 65536, y1, zb, wb);
        relu_fused<<<M_EDGES / 4, 256, 0, stream>>>(y1, wb, zb, en, eoff, eadj, xb);
    }

    dotp<<<M_EDGES / 4, 256, 0, stream>>>(xb, WL, p);
    out_nodes<<<(NN_NODES + 255) / 256, 256, 0, stream>>>(p, noff, nadj, out);
}

// Round 3
// 1241.336 us; speedup vs baseline: 1.0050x; 1.0050x over previous
//
#include <hip/hip_runtime.h>

#define M_EDGES 150000
#define NN_NODES 50000
#define N_TRIS  100000
#define F 256
#define NLAYERS 4

// unified GEMM: virtual A = [x (150k) ; s (50k) ; q (100k)], 256 cols each
// Full-width tiles now: BM=128 x BN=256 per block.
#define T0 1172                  // ceil(150000/128)
#define T1 391                   // ceil(50000/128)
#define T2 782                   // ceil(100000/128)
#define NTILES (T0 + T1 + T2)    // 2345
#define NT_PAD 2352              // 8 * ceil(NTILES/8)
#define TPX 294                  // NT_PAD / 8 tiles per XCD

typedef __attribute__((ext_vector_type(8))) __bf16 bf16x8;
typedef __attribute__((ext_vector_type(4))) float f32x4;

__device__ inline unsigned short f2bf(float f) {
    unsigned int u = __float_as_uint(f);
    u += 0x7fff + ((u >> 16) & 1);
    return (unsigned short)(u >> 16);
}
__device__ inline float bf2f(unsigned short h) {
    return __uint_as_float(((unsigned int)h) << 16);
}

__device__ inline void async16(const void* g, void* l) {
    __builtin_amdgcn_global_load_lds(
        (const __attribute__((address_space(1))) void*)g,
        (__attribute__((address_space(3))) void*)l, 16, 0, 0);
}

// ---------------------------------------------------------------------------
// Unified bf16 MFMA GEMM over 3 row-segments:
//   seg0: y1 = x @ W1   (150000 rows)
//   seg1: z  = s @ W0   (50000 rows)   [B1 pushed through W0]
//   seg2: w  = q @ W2   (100000 rows)  [B2^T pushed through W2]
// Weights wt layout: [seg][n][k] (n-major, 256x256 per seg).
//
// R3: FULL-WIDTH tiles. R1 (dbuf+drain0) and R2 (3-buf counted vmcnt) were
// both NULL on the old 128x128 4-wave structure -- matching learn_hip m232
// (counted-vmcnt pipelining not reproducible on the 4-wave quadrant). The
// old structure also staged every A tile TWICE (bn=0/1). Now: one block =
// 128 rows x 256 cols, 512 threads / 8 waves (2 wm x 4 wn), single 24KB
// LDS buffer, R0-style sync (best measured). A staged once: LDS round-trip
// 600->450MB, L2 A-reads -150MB, 2 blocks/CU x 8 waves resident.
// XOR-swizzled LDS (conflict-free, verified). Epilogue uses SWAPPED mfma
// operands -> lane holds 4 consecutive output cols -> ushort4 stores.
// ---------------------------------------------------------------------------
__global__ __launch_bounds__(512) void gemm_mfma(
    const unsigned short* __restrict__ xb,
    const unsigned short* __restrict__ sb,
    const unsigned short* __restrict__ qb,
    const unsigned short* __restrict__ wt,
    unsigned short* __restrict__ y1,
    unsigned short* __restrict__ zb,
    unsigned short* __restrict__ wb)
{
    __shared__ unsigned short As[128 * 32];   // 8 KB
    __shared__ unsigned short Bs[256 * 32];   // 16 KB

    const int b    = blockIdx.x;
    const int xcd  = b & 7;
    const int idx  = b >> 3;
    const int tile = xcd * TPX + idx;         // chunked per-XCD, bijective
    if (tile >= NTILES) return;

    int seg, tloc;
    if (tile < T0)            { seg = 0; tloc = tile; }
    else if (tile < T0 + T1)  { seg = 1; tloc = tile - T0; }
    else                      { seg = 2; tloc = tile - T0 - T1; }
    const unsigned short* Asrc = (seg == 0) ? xb : (seg == 1) ? sb : qb;
    const int nrows = (seg == 0) ? M_EDGES : (seg == 1) ? NN_NODES : N_TRIS;
    const unsigned short* wsel = wt + seg * 65536;
    unsigned short* dst = (seg == 0) ? y1 : (seg == 1) ? zb : wb;

    const int tid  = threadIdx.x;
    const int bm0  = tloc * 128;
    const int wid  = tid >> 6;
    const int lane = tid & 63;
    const int lm   = lane & 15;
    const int lh   = lane >> 4;
    const int wm   = wid >> 2;                // 0..1  (64-row half)
    const int wn   = wid & 3;                 // 0..3  (64-col quarter)
    const int wbase = tid & ~63;

    f32x4 cacc[4][4];
#pragma unroll
    for (int i = 0; i < 4; i++)
#pragma unroll
        for (int j = 0; j < 4; j++) cacc[i][j] = (f32x4){0.f, 0.f, 0.f, 0.f};

    for (int k0 = 0; k0 < 256; k0 += 32) {
        // A: 128 rows x 32k = 512 granules of 16B, one per thread
        {
            int row = tid >> 2;                       // 0..127
            int g   = (tid & 3) ^ ((row >> 1) & 3);   // swizzled k-granule
            int gr  = bm0 + row;
            if (gr > nrows - 1) gr = nrows - 1;
            async16(Asrc + (size_t)gr * 256 + k0 + g * 8,
                    As + (size_t)wbase * 8);
        }
        // B: 256 rows x 32k = 1024 granules, two per thread
#pragma unroll
        for (int ss = 0; ss < 2; ss++) {
            int i   = ss * 512 + tid;
            int row = i >> 2;                         // 0..255
            int g   = (i & 3) ^ ((row >> 1) & 3);
            async16(wsel + (size_t)row * 256 + k0 + g * 8,
                    Bs + (size_t)(ss * 512 + wbase) * 8);
        }
        asm volatile("s_waitcnt vmcnt(0)" ::: "memory");
        __syncthreads();

        bf16x8 a[4], bfr[4];
#pragma unroll
        for (int i = 0; i < 4; i++) {
            int rr = wm * 64 + i * 16 + lm;
            a[i] = *(const bf16x8*)(As + rr * 32 + ((lh ^ ((rr >> 1) & 3)) * 8));
        }
#pragma unroll
        for (int j = 0; j < 4; j++) {
            int rr = wn * 64 + j * 16 + lm;
            bfr[j] = *(const bf16x8*)(Bs + rr * 32 + ((lh ^ ((rr >> 1) & 3)) * 8));
        }
        // swapped operands: result lane holds row m=lm, cols n=lh*4+reg
#pragma unroll
        for (int i = 0; i < 4; i++)
#pragma unroll
            for (int j = 0; j < 4; j++)
                cacc[i][j] = __builtin_amdgcn_mfma_f32_16x16x32_bf16(
                    bfr[j], a[i], cacc[i][j], 0, 0, 0);
        __syncthreads();
    }

#pragma unroll
    for (int i = 0; i < 4; i++) {
        int grow = bm0 + wm * 64 + i * 16 + lm;
        if (grow < nrows) {
#pragma unroll
            for (int j = 0; j < 4; j++) {
                int col = wn * 64 + j * 16 + lh * 4;
                ushort4 r;
                r.x = f2bf(cacc[i][j][0]);
                r.y = f2bf(cacc[i][j][1]);
                r.z = f2bf(cacc[i][j][2]);
                r.w = f2bf(cacc[i][j][3]);
                *(ushort4*)(dst + (size_t)grow * 256 + col) = r;
            }
        }
    }
}

// ---------------------------------------------------------------------------
// CSR build
// ---------------------------------------------------------------------------
__global__ __launch_bounds__(256) void count_nodes(
    const int* __restrict__ en, int* __restrict__ cnt)
{
    int e = blockIdx.x * 256 + threadIdx.x;
    if (e < M_EDGES) {
        atomicAdd(&cnt[en[2 * e]], 1);
        atomicAdd(&cnt[en[2 * e + 1]], 1);
    }
}

__global__ __launch_bounds__(256) void count_tris(
    const int* __restrict__ te, int* __restrict__ cnt)
{
    int t = blockIdx.x * 256 + threadIdx.x;
    if (t < N_TRIS) {
#pragma unroll
        for (int k = 0; k < 3; k++) atomicAdd(&cnt[te[3 * t + k]], 1);
    }
}

__global__ __launch_bounds__(256) void scan_block(
    const int* __restrict__ cnt, int* __restrict__ off,
    int* __restrict__ partial, int n)
{
    __shared__ int s[256];
    int t = threadIdx.x;
    int gid = blockIdx.x * 256 + t;
    int v = (gid < n) ? cnt[gid] : 0;
    s[t] = v;
    __syncthreads();
    for (int o = 1; o < 256; o <<= 1) {
        int x = (t >= o) ? s[t - o] : 0;
        __syncthreads();
        s[t] += x;
        __syncthreads();
    }
    if (gid < n) off[gid] = s[t] - v;
    if (t == 255) partial[blockIdx.x] = s[255];
}

__global__ __launch_bounds__(1024) void scan_partial(int* __restrict__ partial, int nb)
{
    __shared__ int s[1024];
    int t = threadIdx.x;
    int v = (t < nb) ? partial[t] : 0;
    s[t] = v;
    __syncthreads();
    for (int o = 1; o < 1024; o <<= 1) {
        int x = (t >= o) ? s[t - o] : 0;
        __syncthreads();
        s[t] += x;
        __syncthreads();
    }
    if (t < nb) partial[t] = s[t] - v;
}

__global__ __launch_bounds__(256) void scan_add(
    int* __restrict__ off, int* __restrict__ cursor,
    const int* __restrict__ partial, int n, int total)
{
    int gid = blockIdx.x * 256 + threadIdx.x;
    if (gid == 0) off[n] = total;
    if (gid < n) {
        int o = off[gid] + partial[blockIdx.x];
        off[gid] = o;
        cursor[gid] = o;
    }
}

__global__ __launch_bounds__(256) void fill_nodes(
    const int* __restrict__ en, int* __restrict__ cursor, int* __restrict__ adj)
{
    int e = blockIdx.x * 256 + threadIdx.x;
    if (e < M_EDGES) {
        int u = en[2 * e], v = en[2 * e + 1];
        adj[atomicAdd(&cursor[u], 1)] = (e << 1);        // u endpoint: minus
        adj[atomicAdd(&cursor[v], 1)] = (e << 1) | 1;    // v endpoint: plus
    }
}

__global__ __launch_bounds__(256) void fill_tris(
    const int* __restrict__ te, const int* __restrict__ ts,
    int* __restrict__ cursor, int* __restrict__ adj)
{
    int t = blockIdx.x * 256 + threadIdx.x;
    if (t < N_TRIS) {
#pragma unroll
        for (int k = 0; k < 3; k++) {
            int e = te[3 * t + k];
            int neg = (ts[3 * t + k] < 0) ? 1 : 0;
            adj[atomicAdd(&cursor[e], 1)] = (t << 1) | neg;
        }
    }
}

// ---------------------------------------------------------------------------
// Aggregation pass (pre-GEMM):
//   blocks [0, ZN_BLOCKS)        : s[n] = sum (+/-) x[e]   (node CSR)
//   blocks [ZN_BLOCKS, +WT)      : q[t] = sum s_k * x[e_k] (tri direct)
// ---------------------------------------------------------------------------
#define ZN_BLOCKS (NN_NODES / 4)
#define WT_BLOCKS (N_TRIS / 4)

__global__ __launch_bounds__(256) void agg_fused(
    const unsigned short* __restrict__ xb,
    const int* __restrict__ noff,
    const int* __restrict__ nadj,
    unsigned short* __restrict__ sbuf,
    const int* __restrict__ te,
    const int* __restrict__ ts,
    unsigned short* __restrict__ qbuf)
{
    int lane = threadIdx.x & 63;
    int f = lane * 4;
    if (blockIdx.x < ZN_BLOCKS) {
        int n = blockIdx.x * 4 + (threadIdx.x >> 6);
        int beg = noff[n], end = noff[n + 1];
        float ax = 0.f, ay = 0.f, az = 0.f, aw = 0.f;
        int i = beg;
        for (; i + 1 < end; i += 2) {
            int ea = nadj[i], eb = nadj[i + 1];
            float sa = (ea & 1) ? 1.f : -1.f;
            float sgb = (eb & 1) ? 1.f : -1.f;
            ushort4 va = *(const ushort4*)(xb + (size_t)(ea >> 1) * 256 + f);
            ushort4 vb = *(const ushort4*)(xb + (size_t)(eb >> 1) * 256 + f);
            ax += sa * bf2f(va.x) + sgb * bf2f(vb.x);
            ay += sa * bf2f(va.y) + sgb * bf2f(vb.y);
            az += sa * bf2f(va.z) + sgb * bf2f(vb.z);
            aw += sa * bf2f(va.w) + sgb * bf2f(vb.w);
        }
        if (i < end) {
            int ea = nadj[i];
            float sa = (ea & 1) ? 1.f : -1.f;
            ushort4 va = *(const ushort4*)(xb + (size_t)(ea >> 1) * 256 + f);
            ax += sa * bf2f(va.x);
            ay += sa * bf2f(va.y);
            az += sa * bf2f(va.z);
            aw += sa * bf2f(va.w);
        }
        ushort4 r;
        r.x = f2bf(ax); r.y = f2bf(ay); r.z = f2bf(az); r.w = f2bf(aw);
        *(ushort4*)(sbuf + (size_t)n * 256 + f) = r;
    } else {
        int t = (blockIdx.x - ZN_BLOCKS) * 4 + (threadIdx.x >> 6);
        int e0 = te[3 * t + 0], e1 = te[3 * t + 1], e2 = te[3 * t + 2];
        float s0 = (float)ts[3 * t + 0];
        float s1 = (float)ts[3 * t + 1];
        float s2 = (float)ts[3 * t + 2];
        ushort4 a4 = *(const ushort4*)(xb + (size_t)e0 * 256 + f);
        ushort4 b4 = *(const ushort4*)(xb + (size_t)e1 * 256 + f);
        ushort4 d4 = *(const ushort4*)(xb + (size_t)e2 * 256 + f);
        ushort4 r;
        r.x = f2bf(s0 * bf2f(a4.x) + s1 * bf2f(b4.x) + s2 * bf2f(d4.x));
        r.y = f2bf(s0 * bf2f(a4.y) + s1 * bf2f(b4.y) + s2 * bf2f(d4.y));
        r.z = f2bf(s0 * bf2f(a4.z) + s1 * bf2f(b4.z) + s2 * bf2f(d4.z));
        r.w = f2bf(s0 * bf2f(a4.w) + s1 * bf2f(b4.w) + s2 * bf2f(d4.w));
        *(ushort4*)(qbuf + (size_t)t * 256 + f) = r;
    }
}

// ---------------------------------------------------------------------------
// x_next[e] = relu( y1[e] + sum s*w[t] + z[v]-z[u] )
// last==0: write x_next to xb.
// last==1: skip xb store; p[e] = relu_row . W0_L (fused dotp; saves the
//          76.8MB x write + 76.8MB x re-read + one kernel).
// ---------------------------------------------------------------------------
__global__ __launch_bounds__(256) void relu_fused(
    const unsigned short* __restrict__ y1,
    const unsigned short* __restrict__ w,
    const unsigned short* __restrict__ z,
    const int* __restrict__ en,
    const int* __restrict__ eoff,
    const int* __restrict__ eadj,
    unsigned short* __restrict__ xb,
    const float* __restrict__ wl,
    float* __restrict__ p,
    int last)
{
    int e = blockIdx.x * 4 + (threadIdx.x >> 6);
    int lane = threadIdx.x & 63;
    int f = lane * 4;
    int u = en[2 * e], v = en[2 * e + 1];
    int beg = eoff[e], end = eoff[e + 1];
    ushort4 a4 = *(const ushort4*)(y1 + (size_t)e * 256 + f);
    ushort4 zv = *(const ushort4*)(z + (size_t)v * 256 + f);
    ushort4 zu = *(const ushort4*)(z + (size_t)u * 256 + f);
    float sx = bf2f(a4.x) + bf2f(zv.x) - bf2f(zu.x);
    float sy = bf2f(a4.y) + bf2f(zv.y) - bf2f(zu.y);
    float sz = bf2f(a4.z) + bf2f(zv.z) - bf2f(zu.z);
    float sw = bf2f(a4.w) + bf2f(zv.w) - bf2f(zu.w);
    int i = beg;
    for (; i + 1 < end; i += 2) {
        int ta = eadj[i], tb = eadj[i + 1];
        float sa = (ta & 1) ? -1.f : 1.f;
        float sgb = (tb & 1) ? -1.f : 1.f;
        ushort4 wa = *(const ushort4*)(w + (size_t)(ta >> 1) * 256 + f);
        ushort4 wbv = *(const ushort4*)(w + (size_t)(tb >> 1) * 256 + f);
        sx += sa * bf2f(wa.x) + sgb * bf2f(wbv.x);
        sy += sa * bf2f(wa.y) + sgb * bf2f(wbv.y);
        sz += sa * bf2f(wa.z) + sgb * bf2f(wbv.z);
        sw += sa * bf2f(wa.w) + sgb * bf2f(wbv.w);
    }
    if (i < end) {
        int ta = eadj[i];
        float sa = (ta & 1) ? -1.f : 1.f;
        ushort4 wa = *(const ushort4*)(w + (size_t)(ta >> 1) * 256 + f);
        sx += sa * bf2f(wa.x);
        sy += sa * bf2f(wa.y);
        sz += sa * bf2f(wa.z);
        sw += sa * bf2f(wa.w);
    }
    sx = fmaxf(sx, 0.f);
    sy = fmaxf(sy, 0.f);
    sz = fmaxf(sz, 0.f);
    sw = fmaxf(sw, 0.f);
    if (!last) {
        ushort4 r;
        r.x = f2bf(sx); r.y = f2bf(sy); r.z = f2bf(sz); r.w = f2bf(sw);
        *(ushort4*)(xb + (size_t)e * 256 + f) = r;
    } else {
        float4 wv = *(const float4*)(wl + f);
        float s = sx * wv.x + sy * wv.y + sz * wv.z + sw * wv.w;
#pragma unroll
        for (int off = 32; off > 0; off >>= 1)
            s += __shfl_down(s, off, 64);
        if (lane == 0) p[e] = s;
    }
}

__global__ __launch_bounds__(256) void out_nodes(
    const float* __restrict__ p,
    const int* __restrict__ noff,
    const int* __restrict__ nadj,
    float* __restrict__ out)
{
    int n = blockIdx.x * 256 + threadIdx.x;
    if (n >= NN_NODES) return;
    int beg = noff[n], end = noff[n + 1];
    float s = 0.f;
    for (int i = beg; i < end; i++) {
        int ent = nadj[i];
        float sg = (ent & 1) ? 1.f : -1.f;
        s += sg * p[ent >> 1];
    }
    out[n] = s;
}

// ---------------------------------------------------------------------------
// Conversions
// ---------------------------------------------------------------------------
__global__ __launch_bounds__(256) void cvt_x(
    const float* __restrict__ x, unsigned short* __restrict__ xb)
{
    int idx = blockIdx.x * 256 + threadIdx.x;
    float4 v = *(const float4*)(x + (size_t)idx * 4);
    ushort4 r;
    r.x = f2bf(v.x); r.y = f2bf(v.y); r.z = f2bf(v.z); r.w = f2bf(v.w);
    *(ushort4*)(xb + (size_t)idx * 4) = r;
}

// wt[l][seg][n][k], seg order = (W1, W0, W2) matching GEMM segments
__global__ __launch_bounds__(256) void cvt_w(
    const float* __restrict__ W0, const float* __restrict__ W1,
    const float* __restrict__ W2, unsigned short* __restrict__ wt)
{
    int idx = blockIdx.x * 256 + threadIdx.x;   // 4*3*65536 total
    int l = idx / (3 * 65536);
    int rem = idx - l * (3 * 65536);
    int seg = rem >> 16;
    int n = (rem >> 8) & 255;
    int k = rem & 255;
    const float* src = (seg == 0) ? W1 : (seg == 1) ? W0 : W2;
    wt[idx] = f2bf(src[(size_t)l * 65536 + k * 256 + n]);
}

extern "C" void kernel_launch(void* const* d_in, const int* in_sizes, int n_in,
                              void* d_out, int out_size, void* d_ws, size_t ws_size,
                              hipStream_t stream)
{
    const float* x0  = (const float*)d_in[0];
    const float* W0s = (const float*)d_in[1];
    const float* W1s = (const float*)d_in[2];
    const float* W2s = (const float*)d_in[3];
    const float* WL  = (const float*)d_in[4];
    const int*   en  = (const int*)d_in[5];
    const int*   te  = (const int*)d_in[6];
    const int*   ts  = (const int*)d_in[7];
    float* out = (float*)d_out;

    const size_t MF = (size_t)M_EDGES * F;
    unsigned short* xb = (unsigned short*)d_ws;          // MF
    unsigned short* y1 = xb + MF;                        // MF
    unsigned short* sbuf = y1 + MF;                      // NN*256
    unsigned short* qbuf = sbuf + (size_t)NN_NODES * 256;// N_TRIS*256
    unsigned short* wt = qbuf + (size_t)N_TRIS * 256;    // 4*3*65536
    unsigned short* wb = wt + (size_t)4 * 3 * 65536;     // N_TRIS*256
    unsigned short* zb = wb + (size_t)N_TRIS * 256;      // NN*256
    float* p = (float*)(zb + (size_t)NN_NODES * 256);    // M f32
    int* noff = (int*)(p + M_EDGES);                     // NN+1
    int* ncur = noff + (NN_NODES + 1);                   // NN
    int* nadj = ncur + NN_NODES;                         // 2*M
    int* eoff = nadj + 2 * M_EDGES;                      // M+1
    int* ecur = eoff + (M_EDGES + 1);                    // M
    int* eadj = ecur + M_EDGES;                          // 3*N_TRIS
    int* part = eadj + 3 * N_TRIS;                       // 1024

    cvt_w<<<(4 * 3 * 65536) / 256, 256, 0, stream>>>(W0s, W1s, W2s, wt);
    cvt_x<<<(int)(MF / 4 / 256), 256, 0, stream>>>(x0, xb);

    const int nbN = (NN_NODES + 255) / 256;
    const int nbE = (M_EDGES + 255) / 256;
    hipMemsetAsync(ncur, 0, NN_NODES * sizeof(int), stream);
    hipMemsetAsync(ecur, 0, M_EDGES * sizeof(int), stream);
    count_nodes<<<nbE, 256, 0, stream>>>(en, ncur);
    count_tris<<<(N_TRIS + 255) / 256, 256, 0, stream>>>(te, ecur);
    scan_block<<<nbN, 256, 0, stream>>>(ncur, noff, part, NN_NODES);
    scan_partial<<<1, 1024, 0, stream>>>(part, nbN);
    scan_add<<<nbN, 256, 0, stream>>>(noff, ncur, part, NN_NODES, 2 * M_EDGES);
    fill_nodes<<<nbE, 256, 0, stream>>>(en, ncur, nadj);
    scan_block<<<nbE, 256, 0, stream>>>(ecur, eoff, part, M_EDGES);
    scan_partial<<<1, 1024, 0, stream>>>(part, nbE);
    scan_add<<<nbE, 256, 0, stream>>>(eoff, ecur, part, M_EDGES, 3 * N_TRIS);
    fill_tris<<<(N_TRIS + 255) / 256, 256, 0, stream>>>(te, ts, ecur, eadj);

    for (int l = 0; l < NLAYERS; l++) {
        agg_fused<<<ZN_BLOCKS + WT_BLOCKS, 256, 0, stream>>>(
            xb, noff, nadj, sbuf, te, ts, qbuf);
        gemm_mfma<<<NT_PAD, 512, 0, stream>>>(
            xb, sbuf, qbuf, wt + (size_t)l * 3 * 65536, y1, zb, wb);
        relu_fused<<<M_EDGES / 4, 256, 0, stream>>>(
            y1, wb, zb, en, eoff, eadj, xb, WL, p, (l == NLAYERS - 1) ? 1 : 0);
    }

    out_nodes<<<(NN_NODES + 255) / 256, 256, 0, stream>>>(p, noff, nadj, out);
}

// Round 5
// 1205.408 us; speedup vs baseline: 1.0350x; 1.0298x over previous
//
#include <hip/hip_runtime.h>

#define M_EDGES 150000
#define NN_NODES 50000
#define N_TRIS  100000
#define F 256
#define NLAYERS 4

// virtual A rows = [x (150k) ; s (50k) ; q (100k)], 128-row tiles
#define T0 1172                  // ceil(150000/128)  -> gemm_y1_relu
#define T1 391                   // ceil(50000/128)   -> gemm_zw seg1
#define T2 782                   // ceil(100000/128)  -> gemm_zw seg2
#define TZW (T1 + T2)            // 1173
#define GR_PAD 1176              // 8 * 147, grid for both gemms
#define TPX8 147                 // tiles per XCD

typedef __attribute__((ext_vector_type(8))) __bf16 bf16x8;
typedef __attribute__((ext_vector_type(4))) float f32x4;

__device__ inline unsigned short f2bf(float f) {
    unsigned int u = __float_as_uint(f);
    u += 0x7fff + ((u >> 16) & 1);
    return (unsigned short)(u >> 16);
}
__device__ inline float bf2f(unsigned short h) {
    return __uint_as_float(((unsigned int)h) << 16);
}

__device__ inline void async16(const void* g, void* l) {
    __builtin_amdgcn_global_load_lds(
        (const __attribute__((address_space(1))) void*)g,
        (__attribute__((address_space(3))) void*)l, 16, 0, 0);
}

// ---------------------------------------------------------------------------
// R4b: resubmit of R4 (container infra flake, no data). Design:
// split GEMM + fuse relu into the y1 epilogue.
// R0-R3 established: gemm K-loop scheduling is invariant (~100us) across
// drain-0 / counted-vmcnt / 4-wave / 8-wave variants -> pivot to traffic.
// relu_fused was a pure consumer of y1: gemm wrote y1 (76.8MB), relu re-read
// it (76.8MB). Now:
//   gemm_zw      : z = s@W0, w = q@W2            (1173 tiles)
//   gemm_y1_relu : x_next = relu(x@W1 + gathers) (1172 tiles, in-place xb)
// y1 buffer eliminated entirely (-153.6 MB/layer HBM-side traffic).
// Epilogue stages the C-tile in LDS (XOR-swizzled rows, reusing the As/Bs
// space), then each wave does relu_fused's exact 512B/wave coalesced gather
// pattern. In-place xb write is race-free: block i reads/writes only rows
// of tile i. Last layer: fused W0_L dot -> p[e], no x write.
// ---------------------------------------------------------------------------

// shared K-loop body (single 24KB buffer, R0-style sync: best measured)
#define GEMM_KLOOP(Asrc, wsel, nrows)                                       \
    for (int k0 = 0; k0 < 256; k0 += 32) {                                  \
        {                                                                   \
            int row = tid >> 2;                                             \
            int g   = (tid & 3) ^ ((row >> 1) & 3);                         \
            int gr  = bm0 + row;                                            \
            if (gr > (nrows) - 1) gr = (nrows) - 1;                         \
            async16((Asrc) + (size_t)gr * 256 + k0 + g * 8,                 \
                    As + (size_t)wbase * 8);                                \
        }                                                                   \
        _Pragma("unroll")                                                   \
        for (int ss = 0; ss < 2; ss++) {                                    \
            int i   = ss * 512 + tid;                                       \
            int row = i >> 2;                                               \
            int g   = (i & 3) ^ ((row >> 1) & 3);                           \
            async16((wsel) + (size_t)row * 256 + k0 + g * 8,                \
                    Bs + (size_t)(ss * 512 + wbase) * 8);                   \
        }                                                                   \
        asm volatile("s_waitcnt vmcnt(0)" ::: "memory");                    \
        __syncthreads();                                                    \
        bf16x8 a[4], bfr[4];                                                \
        _Pragma("unroll")                                                   \
        for (int i = 0; i < 4; i++) {                                       \
            int rr = wm * 64 + i * 16 + lm;                                 \
            a[i] = *(const bf16x8*)(As + rr * 32 +                          \
                                    ((lh ^ ((rr >> 1) & 3)) * 8));          \
        }                                                                   \
        _Pragma("unroll")                                                   \
        for (int j = 0; j < 4; j++) {                                       \
            int rr = wn * 64 + j * 16 + lm;                                 \
            bfr[j] = *(const bf16x8*)(Bs + rr * 32 +                        \
                                      ((lh ^ ((rr >> 1) & 3)) * 8));        \
        }                                                                   \
        _Pragma("unroll")                                                   \
        for (int i = 0; i < 4; i++)                                         \
            _Pragma("unroll")                                               \
            for (int j = 0; j < 4; j++)                                     \
                cacc[i][j] = __builtin_amdgcn_mfma_f32_16x16x32_bf16(       \
                    bfr[j], a[i], cacc[i][j], 0, 0, 0);                     \
        __syncthreads();                                                    \
    }

__global__ __launch_bounds__(512) void gemm_zw(
    const unsigned short* __restrict__ sb,
    const unsigned short* __restrict__ qb,
    const unsigned short* __restrict__ wt,
    unsigned short* __restrict__ zb,
    unsigned short* __restrict__ wb)
{
    __shared__ unsigned short As[128 * 32];   // 8 KB
    __shared__ unsigned short Bs[256 * 32];   // 16 KB

    const int b    = blockIdx.x;
    const int tile = (b & 7) * TPX8 + (b >> 3);
    if (tile >= TZW) return;

    int seg, tloc;
    if (tile < T1) { seg = 1; tloc = tile; }
    else           { seg = 2; tloc = tile - T1; }
    const unsigned short* Asrc = (seg == 1) ? sb : qb;
    const int nrows = (seg == 1) ? NN_NODES : N_TRIS;
    const unsigned short* wsel = wt + seg * 65536;
    unsigned short* dst = (seg == 1) ? zb : wb;

    const int tid  = threadIdx.x;
    const int bm0  = tloc * 128;
    const int wid  = tid >> 6;
    const int lane = tid & 63;
    const int lm   = lane & 15;
    const int lh   = lane >> 4;
    const int wm   = wid >> 2;
    const int wn   = wid & 3;
    const int wbase = tid & ~63;

    f32x4 cacc[4][4];
#pragma unroll
    for (int i = 0; i < 4; i++)
#pragma unroll
        for (int j = 0; j < 4; j++) cacc[i][j] = (f32x4){0.f, 0.f, 0.f, 0.f};

    GEMM_KLOOP(Asrc, wsel, nrows)

#pragma unroll
    for (int i = 0; i < 4; i++) {
        int grow = bm0 + wm * 64 + i * 16 + lm;
        if (grow < nrows) {
#pragma unroll
            for (int j = 0; j < 4; j++) {
                int col = wn * 64 + j * 16 + lh * 4;
                ushort4 r;
                r.x = f2bf(cacc[i][j][0]);
                r.y = f2bf(cacc[i][j][1]);
                r.z = f2bf(cacc[i][j][2]);
                r.w = f2bf(cacc[i][j][3]);
                *(ushort4*)(dst + (size_t)grow * 256 + col) = r;
            }
        }
    }
}

__global__ __launch_bounds__(512) void gemm_y1_relu(
    unsigned short* __restrict__ xb,          // A source AND x_next dst
    const unsigned short* __restrict__ wt,    // seg0 weights (W1)
    const unsigned short* __restrict__ wb,    // tri rows (q@W2)
    const unsigned short* __restrict__ zb,    // node rows (s@W0)
    const int* __restrict__ en,
    const int* __restrict__ eoff,
    const int* __restrict__ eadj,
    const float* __restrict__ wl,
    float* __restrict__ p,
    int last)
{
    // 64 KB: K-loop uses [0,24KB) as As|Bs; epilogue reuses all of it
    // as the 128x256 bf16 C-tile.
    __shared__ __align__(16) unsigned short smem[128 * 256];
    unsigned short* const As = smem;              // 128*32
    unsigned short* const Bs = smem + 128 * 32;   // 256*32

    const int b    = blockIdx.x;
    const int tile = (b & 7) * TPX8 + (b >> 3);
    if (tile >= T0) return;

    const int tid  = threadIdx.x;
    const int bm0  = tile * 128;
    const int wid  = tid >> 6;
    const int lane = tid & 63;
    const int lm   = lane & 15;
    const int lh   = lane >> 4;
    const int wm   = wid >> 2;
    const int wn   = wid & 3;
    const int wbase = tid & ~63;

    f32x4 cacc[4][4];
#pragma unroll
    for (int i = 0; i < 4; i++)
#pragma unroll
        for (int j = 0; j < 4; j++) cacc[i][j] = (f32x4){0.f, 0.f, 0.f, 0.f};

    GEMM_KLOOP(xb, wt, M_EDGES)

    // --- stage C tile to LDS, bf16, XOR-swizzled by row (avoids the
    // bank-column conflict a linear 512B-stride layout would have) ---
#pragma unroll
    for (int i = 0; i < 4; i++) {
        int lr  = wm * 64 + i * 16 + lm;
        int key = (lr & 7) << 4;
#pragma unroll
        for (int j = 0; j < 4; j++) {
            int colb = wn * 128 + j * 32 + lh * 8;   // byte offset in row
            ushort4 r;
            r.x = f2bf(cacc[i][j][0]);
            r.y = f2bf(cacc[i][j][1]);
            r.z = f2bf(cacc[i][j][2]);
            r.w = f2bf(cacc[i][j][3]);
            *(ushort4*)((char*)smem + (size_t)lr * 512 + (colb ^ key)) = r;
        }
    }
    __syncthreads();

    // --- fused relu: one wave handles one edge row at a time with the
    // fully-coalesced 512B/wave gather pattern ---
    const int f = lane * 4;
    for (int r8 = 0; r8 < 16; r8++) {
        int lr = r8 * 8 + wid;
        int e  = bm0 + lr;
        if (e >= M_EDGES) break;   // wave-uniform (tail tile only)
        ushort4 yv = *(const ushort4*)((const char*)smem + (size_t)lr * 512 +
                                       ((lane * 8) ^ ((lr & 7) << 4)));
        int u = en[2 * e], v = en[2 * e + 1];
        ushort4 zv4 = *(const ushort4*)(zb + (size_t)v * 256 + f);
        ushort4 zu4 = *(const ushort4*)(zb + (size_t)u * 256 + f);
        float sx = bf2f(yv.x) + bf2f(zv4.x) - bf2f(zu4.x);
        float sy = bf2f(yv.y) + bf2f(zv4.y) - bf2f(zu4.y);
        float sz = bf2f(yv.z) + bf2f(zv4.z) - bf2f(zu4.z);
        float sw = bf2f(yv.w) + bf2f(zv4.w) - bf2f(zu4.w);
        int beg = eoff[e], end = eoff[e + 1];
        int i2 = beg;
        for (; i2 + 1 < end; i2 += 2) {
            int ta = eadj[i2], tb = eadj[i2 + 1];
            float sa  = (ta & 1) ? -1.f : 1.f;
            float sgb = (tb & 1) ? -1.f : 1.f;
            ushort4 wa  = *(const ushort4*)(wb + (size_t)(ta >> 1) * 256 + f);
            ushort4 wbv = *(const ushort4*)(wb + (size_t)(tb >> 1) * 256 + f);
            sx += sa * bf2f(wa.x) + sgb * bf2f(wbv.x);
            sy += sa * bf2f(wa.y) + sgb * bf2f(wbv.y);
            sz += sa * bf2f(wa.z) + sgb * bf2f(wbv.z);
            sw += sa * bf2f(wa.w) + sgb * bf2f(wbv.w);
        }
        if (i2 < end) {
            int ta = eadj[i2];
            float sa = (ta & 1) ? -1.f : 1.f;
            ushort4 wa = *(const ushort4*)(wb + (size_t)(ta >> 1) * 256 + f);
            sx += sa * bf2f(wa.x);
            sy += sa * bf2f(wa.y);
            sz += sa * bf2f(wa.z);
            sw += sa * bf2f(wa.w);
        }
        sx = fmaxf(sx, 0.f);
        sy = fmaxf(sy, 0.f);
        sz = fmaxf(sz, 0.f);
        sw = fmaxf(sw, 0.f);
        if (!last) {
            ushort4 r;
            r.x = f2bf(sx); r.y = f2bf(sy); r.z = f2bf(sz); r.w = f2bf(sw);
            *(ushort4*)(xb + (size_t)e * 256 + f) = r;
        } else {
            float4 wv = *(const float4*)(wl + f);
            float s = sx * wv.x + sy * wv.y + sz * wv.z + sw * wv.w;
#pragma unroll
            for (int off = 32; off > 0; off >>= 1)
                s += __shfl_down(s, off, 64);
            if (lane == 0) p[e] = s;
        }
    }
}

// ---------------------------------------------------------------------------
// CSR build
// ---------------------------------------------------------------------------
__global__ __launch_bounds__(256) void count_nodes(
    const int* __restrict__ en, int* __restrict__ cnt)
{
    int e = blockIdx.x * 256 + threadIdx.x;
    if (e < M_EDGES) {
        atomicAdd(&cnt[en[2 * e]], 1);
        atomicAdd(&cnt[en[2 * e + 1]], 1);
    }
}

__global__ __launch_bounds__(256) void count_tris(
    const int* __restrict__ te, int* __restrict__ cnt)
{
    int t = blockIdx.x * 256 + threadIdx.x;
    if (t < N_TRIS) {
#pragma unroll
        for (int k = 0; k < 3; k++) atomicAdd(&cnt[te[3 * t + k]], 1);
    }
}

__global__ __launch_bounds__(256) void scan_block(
    const int* __restrict__ cnt, int* __restrict__ off,
    int* __restrict__ partial, int n)
{
    __shared__ int s[256];
    int t = threadIdx.x;
    int gid = blockIdx.x * 256 + t;
    int v = (gid < n) ? cnt[gid] : 0;
    s[t] = v;
    __syncthreads();
    for (int o = 1; o < 256; o <<= 1) {
        int x = (t >= o) ? s[t - o] : 0;
        __syncthreads();
        s[t] += x;
        __syncthreads();
    }
    if (gid < n) off[gid] = s[t] - v;
    if (t == 255) partial[blockIdx.x] = s[255];
}

__global__ __launch_bounds__(1024) void scan_partial(int* __restrict__ partial, int nb)
{
    __shared__ int s[1024];
    int t = threadIdx.x;
    int v = (t < nb) ? partial[t] : 0;
    s[t] = v;
    __syncthreads();
    for (int o = 1; o < 1024; o <<= 1) {
        int x = (t >= o) ? s[t - o] : 0;
        __syncthreads();
        s[t] += x;
        __syncthreads();
    }
    if (t < nb) partial[t] = s[t] - v;
}

__global__ __launch_bounds__(256) void scan_add(
    int* __restrict__ off, int* __restrict__ cursor,
    const int* __restrict__ partial, int n, int total)
{
    int gid = blockIdx.x * 256 + threadIdx.x;
    if (gid == 0) off[n] = total;
    if (gid < n) {
        int o = off[gid] + partial[blockIdx.x];
        off[gid] = o;
        cursor[gid] = o;
    }
}

__global__ __launch_bounds__(256) void fill_nodes(
    const int* __restrict__ en, int* __restrict__ cursor, int* __restrict__ adj)
{
    int e = blockIdx.x * 256 + threadIdx.x;
    if (e < M_EDGES) {
        int u = en[2 * e], v = en[2 * e + 1];
        adj[atomicAdd(&cursor[u], 1)] = (e << 1);        // u endpoint: minus
        adj[atomicAdd(&cursor[v], 1)] = (e << 1) | 1;    // v endpoint: plus
    }
}

__global__ __launch_bounds__(256) void fill_tris(
    const int* __restrict__ te, const int* __restrict__ ts,
    int* __restrict__ cursor, int* __restrict__ adj)
{
    int t = blockIdx.x * 256 + threadIdx.x;
    if (t < N_TRIS) {
#pragma unroll
        for (int k = 0; k < 3; k++) {
            int e = te[3 * t + k];
            int neg = (ts[3 * t + k] < 0) ? 1 : 0;
            adj[atomicAdd(&cursor[e], 1)] = (t << 1) | neg;
        }
    }
}

// ---------------------------------------------------------------------------
// Aggregation pass (pre-GEMM):
//   blocks [0, ZN_BLOCKS)        : s[n] = sum (+/-) x[e]   (node CSR)
//   blocks [ZN_BLOCKS, +WT)      : q[t] = sum s_k * x[e_k] (tri direct)
// ---------------------------------------------------------------------------
#define ZN_BLOCKS (NN_NODES / 4)
#define WT_BLOCKS (N_TRIS / 4)

__global__ __launch_bounds__(256) void agg_fused(
    const unsigned short* __restrict__ xb,
    const int* __restrict__ noff,
    const int* __restrict__ nadj,
    unsigned short* __restrict__ sbuf,
    const int* __restrict__ te,
    const int* __restrict__ ts,
    unsigned short* __restrict__ qbuf)
{
    int lane = threadIdx.x & 63;
    int f = lane * 4;
    if (blockIdx.x < ZN_BLOCKS) {
        int n = blockIdx.x * 4 + (threadIdx.x >> 6);
        int beg = noff[n], end = noff[n + 1];
        float ax = 0.f, ay = 0.f, az = 0.f, aw = 0.f;
        int i = beg;
        for (; i + 1 < end; i += 2) {
            int ea = nadj[i], eb = nadj[i + 1];
            float sa = (ea & 1) ? 1.f : -1.f;
            float sgb = (eb & 1) ? 1.f : -1.f;
            ushort4 va = *(const ushort4*)(xb + (size_t)(ea >> 1) * 256 + f);
            ushort4 vb = *(const ushort4*)(xb + (size_t)(eb >> 1) * 256 + f);
            ax += sa * bf2f(va.x) + sgb * bf2f(vb.x);
            ay += sa * bf2f(va.y) + sgb * bf2f(vb.y);
            az += sa * bf2f(va.z) + sgb * bf2f(vb.z);
            aw += sa * bf2f(va.w) + sgb * bf2f(vb.w);
        }
        if (i < end) {
            int ea = nadj[i];
            float sa = (ea & 1) ? 1.f : -1.f;
            ushort4 va = *(const ushort4*)(xb + (size_t)(ea >> 1) * 256 + f);
            ax += sa * bf2f(va.x);
            ay += sa * bf2f(va.y);
            az += sa * bf2f(va.z);
            aw += sa * bf2f(va.w);
        }
        ushort4 r;
        r.x = f2bf(ax); r.y = f2bf(ay); r.z = f2bf(az); r.w = f2bf(aw);
        *(ushort4*)(sbuf + (size_t)n * 256 + f) = r;
    } else {
        int t = (blockIdx.x - ZN_BLOCKS) * 4 + (threadIdx.x >> 6);
        int e0 = te[3 * t + 0], e1 = te[3 * t + 1], e2 = te[3 * t + 2];
        float s0 = (float)ts[3 * t + 0];
        float s1 = (float)ts[3 * t + 1];
        float s2 = (float)ts[3 * t + 2];
        ushort4 a4 = *(const ushort4*)(xb + (size_t)e0 * 256 + f);
        ushort4 b4 = *(const ushort4*)(xb + (size_t)e1 * 256 + f);
        ushort4 d4 = *(const ushort4*)(xb + (size_t)e2 * 256 + f);
        ushort4 r;
        r.x = f2bf(s0 * bf2f(a4.x) + s1 * bf2f(b4.x) + s2 * bf2f(d4.x));
        r.y = f2bf(s0 * bf2f(a4.y) + s1 * bf2f(b4.y) + s2 * bf2f(d4.y));
        r.z = f2bf(s0 * bf2f(a4.z) + s1 * bf2f(b4.z) + s2 * bf2f(d4.z));
        r.w = f2bf(s0 * bf2f(a4.w) + s1 * bf2f(b4.w) + s2 * bf2f(d4.w));
        *(ushort4*)(qbuf + (size_t)t * 256 + f) = r;
    }
}

__global__ __launch_bounds__(256) void out_nodes(
    const float* __restrict__ p,
    const int* __restrict__ noff,
    const int* __restrict__ nadj,
    float* __restrict__ out)
{
    int n = blockIdx.x * 256 + threadIdx.x;
    if (n >= NN_NODES) return;
    int beg = noff[n], end = noff[n + 1];
    float s = 0.f;
    for (int i = beg; i < end; i++) {
        int ent = nadj[i];
        float sg = (ent & 1) ? 1.f : -1.f;
        s += sg * p[ent >> 1];
    }
    out[n] = s;
}

// ---------------------------------------------------------------------------
// Conversions
// ---------------------------------------------------------------------------
__global__ __launch_bounds__(256) void cvt_x(
    const float* __restrict__ x, unsigned short* __restrict__ xb)
{
    int idx = blockIdx.x * 256 + threadIdx.x;
    float4 v = *(const float4*)(x + (size_t)idx * 4);
    ushort4 r;
    r.x = f2bf(v.x); r.y = f2bf(v.y); r.z = f2bf(v.z); r.w = f2bf(v.w);
    *(ushort4*)(xb + (size_t)idx * 4) = r;
}

// wt[l][seg][n][k], seg order = (W1, W0, W2) matching GEMM segments
__global__ __launch_bounds__(256) void cvt_w(
    const float* __restrict__ W0, const float* __restrict__ W1,
    const float* __restrict__ W2, unsigned short* __restrict__ wt)
{
    int idx = blockIdx.x * 256 + threadIdx.x;   // 4*3*65536 total
    int l = idx / (3 * 65536);
    int rem = idx - l * (3 * 65536);
    int seg = rem >> 16;
    int n = (rem >> 8) & 255;
    int k = rem & 255;
    const float* src = (seg == 0) ? W1 : (seg == 1) ? W0 : W2;
    wt[idx] = f2bf(src[(size_t)l * 65536 + k * 256 + n]);
}

extern "C" void kernel_launch(void* const* d_in, const int* in_sizes, int n_in,
                              void* d_out, int out_size, void* d_ws, size_t ws_size,
                              hipStream_t stream)
{
    const float* x0  = (const float*)d_in[0];
    const float* W0s = (const float*)d_in[1];
    const float* W1s = (const float*)d_in[2];
    const float* W2s = (const float*)d_in[3];
    const float* WL  = (const float*)d_in[4];
    const int*   en  = (const int*)d_in[5];
    const int*   te  = (const int*)d_in[6];
    const int*   ts  = (const int*)d_in[7];
    float* out = (float*)d_out;

    const size_t MF = (size_t)M_EDGES * F;
    unsigned short* xb = (unsigned short*)d_ws;          // MF
    unsigned short* y1 = xb + MF;                        // MF (unused now)
    unsigned short* sbuf = y1 + MF;                      // NN*256
    unsigned short* qbuf = sbuf + (size_t)NN_NODES * 256;// N_TRIS*256
    unsigned short* wt = qbuf + (size_t)N_TRIS * 256;    // 4*3*65536
    unsigned short* wb = wt + (size_t)4 * 3 * 65536;     // N_TRIS*256
    unsigned short* zb = wb + (size_t)N_TRIS * 256;      // NN*256
    float* p = (float*)(zb + (size_t)NN_NODES * 256);    // M f32
    int* noff = (int*)(p + M_EDGES);                     // NN+1
    int* ncur = noff + (NN_NODES + 1);                   // NN
    int* nadj = ncur + NN_NODES;                         // 2*M
    int* eoff = nadj + 2 * M_EDGES;                      // M+1
    int* ecur = eoff + (M_EDGES + 1);                    // M
    int* eadj = ecur + M_EDGES;                          // 3*N_TRIS
    int* part = eadj + 3 * N_TRIS;                       // 1024

    cvt_w<<<(4 * 3 * 65536) / 256, 256, 0, stream>>>(W0s, W1s, W2s, wt);
    cvt_x<<<(int)(MF / 4 / 256), 256, 0, stream>>>(x0, xb);

    const int nbN = (NN_NODES + 255) / 256;
    const int nbE = (M_EDGES + 255) / 256;
    hipMemsetAsync(ncur, 0, NN_NODES * sizeof(int), stream);
    hipMemsetAsync(ecur, 0, M_EDGES * sizeof(int), stream);
    count_nodes<<<nbE, 256, 0, stream>>>(en, ncur);
    count_tris<<<(N_TRIS + 255) / 256, 256, 0, stream>>>(te, ecur);
    scan_block<<<nbN, 256, 0, stream>>>(ncur, noff, part, NN_NODES);
    scan_partial<<<1, 1024, 0, stream>>>(part, nbN);
    scan_add<<<nbN, 256, 0, stream>>>(noff, ncur, part, NN_NODES, 2 * M_EDGES);
    fill_nodes<<<nbE, 256, 0, stream>>>(en, ncur, nadj);
    scan_block<<<nbE, 256, 0, stream>>>(ecur, eoff, part, M_EDGES);
    scan_partial<<<1, 1024, 0, stream>>>(part, nbE);
    scan_add<<<nbE, 256, 0, stream>>>(eoff, ecur, part, M_EDGES, 3 * N_TRIS);
    fill_tris<<<(N_TRIS + 255) / 256, 256, 0, stream>>>(te, ts, ecur, eadj);

    for (int l = 0; l < NLAYERS; l++) {
        agg_fused<<<ZN_BLOCKS + WT_BLOCKS, 256, 0, stream>>>(
            xb, noff, nadj, sbuf, te, ts, qbuf);
        gemm_zw<<<GR_PAD, 512, 0, stream>>>(
            sbuf, qbuf, wt + (size_t)l * 3 * 65536, zb, wb);
        gemm_y1_relu<<<GR_PAD, 512, 0, stream>>>(
            xb, wt + (size_t)l * 3 * 65536, wb, zb, en, eoff, eadj,
            WL, p, (l == NLAYERS - 1) ? 1 : 0);
    }

    out_nodes<<<(NN_NODES + 255) / 256, 256, 0, stream>>>(p, noff, nadj, out);
}